// Round 7
// baseline (298.386 us; speedup 1.0000x reference)
//
#include <hip/hip_runtime.h>

// Problem constants
#define K 256
#define D 128
#define HW 1024          // H*W
#define CHW 131072       // D*HW (per-batch stride of z)
#define N_TOT 131072     // B*H*W
#define NELEM 16777216   // N_TOT * D

// Workspace layout (float/dword indices)
#define WS_C2 0
#define WS_ENCSUM 256
#define WS_ENCB 512
#define WS_LOSS 33280
#define WS_FLAGCNT 33281
#define WS_LIST 33282
#define FLAG_CAP 16384
#define WS_PART 49666            // 64 partial copies of (K*D + K)
#define PBLK 64
#define PSTRIDE 33024            // K*D + K
#define WS_CBT (WS_PART + PBLK * PSTRIDE)   // dead region (unused now)
#define WS_CBH 2195972           // bf16-hi swizzled B frags, 16384 dwords (16B aligned)
#define WS_CBL 2212356           // bf16-lo swizzled B frags, 16384 dwords
// total ws: 2228740*4 B = 8.91 MB

// Output layout (float indices, outputs concatenated in return order)
#define OUT_Q 0
#define OUT_IDX 16777216
#define OUT_COMMIT 16908288
#define OUT_CBLOSS 16908289
#define OUT_NEWCB 16908290
#define OUT_NEWCNT 16941058
#define OUT_NEWW 16941314

// Near-tie threshold. GEMM-score worst-case error vs exact is ~3e-6
// (hi/lo bf16 split; fp32 accum; 3-chain reassociation adds ~1e-7).
// 5e-5 keeps ~15-20x margin.
#define TAU 5e-5f
#define MT 64            // n-tile per block in k_main
#define ZST 68           // zs row stride (64 + 4 pad)

typedef __attribute__((ext_vector_type(8))) short short8;
typedef __attribute__((ext_vector_type(4))) float floatx4;

// Split x into truncated-bf16 hi and bf16 lo (hi exact-subtracted remainder).
__device__ __forceinline__ void cvt_split(const float* xv, short8* hi, short8* lo) {
    union U { uint32_t u[4]; short8 s; } H, L;
    #pragma unroll
    for (int p = 0; p < 4; ++p) {
        uint32_t u0 = __float_as_uint(xv[2 * p]);
        uint32_t u1 = __float_as_uint(xv[2 * p + 1]);
        H.u[p] = (u0 >> 16) | (u1 & 0xFFFF0000u);
        float h0 = __uint_as_float(u0 & 0xFFFF0000u);
        float h1 = __uint_as_float(u1 & 0xFFFF0000u);
        float l0 = xv[2 * p] - h0;
        float l1 = xv[2 * p + 1] - h1;
        L.u[p] = (__float_as_uint(l0) >> 16) | (__float_as_uint(l1) & 0xFFFF0000u);
    }
    *hi = H.s; *lo = L.s;
}

// ---------------------------------------------------------------------------
// Kernel 1: blk==0: c2 (numpy pairwise-8) + zero loss/flag. blk 1..16: bf16
// hi/lo split of cb into MFMA-B fragment order.
// ---------------------------------------------------------------------------
__global__ void k_prep(const float* __restrict__ cb, float* __restrict__ ws) {
    #pragma clang fp contract(off)
    const int blk = blockIdx.x, t = threadIdx.x;
    if (blk == 0) {
        int k = t;
        if (k == 0) { ws[WS_LOSS] = 0.0f; ((int*)ws)[WS_FLAGCNT] = 0; }
        const float* row = cb + (size_t)k * D;
        float r[8];
        #pragma unroll
        for (int j = 0; j < 8; ++j) r[j] = row[j] * row[j];
        for (int i = 8; i < D; i += 8) {
            #pragma unroll
            for (int j = 0; j < 8; ++j) r[j] = r[j] + row[i + j] * row[i + j];
        }
        ws[WS_C2 + k] = ((r[0] + r[1]) + (r[2] + r[3])) + ((r[4] + r[5]) + (r[6] + r[7]));
    } else {
        int e = (blk - 1) * 4 + (t >> 6);   // frag id 0..63
        int lane = t & 63;
        int ds = e >> 4, ktg = e & 15;
        int code = ktg * 16 + (lane & 15);
        int d0 = ds * 32 + (lane >> 4) * 8;
        float xv[8];
        #pragma unroll
        for (int j = 0; j < 8; ++j) xv[j] = cb[(size_t)code * D + d0 + j];
        short8 h, l;
        cvt_split(xv, &h, &l);
        union V { short8 s; uint4 u; } Hv, Lv;
        Hv.s = h; Lv.s = l;
        uint32_t* wsu = (uint32_t*)ws;
        reinterpret_cast<uint4*>(wsu + WS_CBH)[e * 64 + lane] = Hv.u;
        reinterpret_cast<uint4*>(wsu + WS_CBL)[e * 64 + lane] = Lv.u;
    }
}

// ---------------------------------------------------------------------------
// Kernel 2: MFMA GEMM-argmax, 2x2 wave split, 3-CHAIN accumulators.
// Wave w = (mh=w>>1, kh=w&1): 2 m-tiles x 128 codes. Per (kt,mt) the score
// is split into 3 INDEPENDENT MFMA chains (aH: Ah*Bh + iv, aM: Ah*Bl,
// aL: Al*Bh) of 4 dependent MFMAs each, summed at fold — 6 live chains/wave
// keep the MFMA pipe fed (old single 12-chain was latency-bound, Util 13%).
// Reassociation error ~1e-7, absorbed by the TAU fallback margin.
// ---------------------------------------------------------------------------
__global__ void __launch_bounds__(256, 3)
k_main(const float* __restrict__ z, const float* __restrict__ cb,
       float* __restrict__ ws, float* __restrict__ out) {
    __shared__ float zs[D * ZST];      // zs[d][n], 34.8 KB
    __shared__ float c2L[K];           // -0.5*c2
    __shared__ float mgB[2][MT];
    __shared__ float mgS[2][MT];
    __shared__ int   mgK[2][MT];
    __shared__ int bkA[MT];
    __shared__ float lsw[4];

    const int t = threadIdx.x;
    const int blk = blockIdx.x;
    const int n0 = blk * MT;
    const int b = n0 >> 10;
    const int hw0 = n0 & 1023;

    // c2 -> LDS (pre-barrier): -0.5f*x is exact scaling.
    c2L[t] = -0.5f * ws[WS_C2 + t];

    // --- stage z tile: zs[d][n] via float4 over hw ---
    {
        const float4* __restrict__ z4 = reinterpret_cast<const float4*>(z);
        const size_t zbase4 = (size_t)b * (CHW / 4) + (hw0 >> 2);
        #pragma unroll
        for (int i = 0; i < 8; ++i) {
            int f = i * 256 + t;
            int dd = f >> 4, n4 = f & 15;
            float4 v = z4[zbase4 + (size_t)dd * (HW / 4) + n4];
            *reinterpret_cast<float4*>(&zs[dd * ZST + 4 * n4]) = v;
        }
    }
    __syncthreads();

    const int lane = t & 63, w = t >> 6;
    const int col = lane & 15, quad = lane >> 4;
    const int kh = w & 1;              // code half: codes kh*128..+128
    const int mh = w >> 1;             // m half: n = mh*32..+32 (2 m-tiles)

    // --- A fragments: convert once, hold in regs (2 mt x 4 dsteps, hi+lo) ---
    short8 Ah[2][4], Al[2][4];
    {
        const int rbase = quad * 8 * ZST + mh * 32 + col;
        #pragma unroll
        for (int mt = 0; mt < 2; ++mt)
            #pragma unroll
            for (int ds = 0; ds < 4; ++ds) {
                float xv[8];
                #pragma unroll
                for (int j = 0; j < 8; ++j)
                    xv[j] = zs[rbase + (ds * 32 + j) * ZST + mt * 16];
                cvt_split(xv, &Ah[mt][ds], &Al[mt][ds]);
            }
    }

    const uint32_t* wsu = (const uint32_t*)ws;
    const uint4* __restrict__ bh4 = reinterpret_cast<const uint4*>(wsu + WS_CBH);
    const uint4* __restrict__ bl4 = reinterpret_cast<const uint4*>(wsu + WS_CBL);

    float best[2][4], second[2][4];
    int bk[2][4];
    #pragma unroll
    for (int mt = 0; mt < 2; ++mt)
        #pragma unroll
        for (int r = 0; r < 4; ++r) { best[mt][r] = -3.4e38f; second[mt][r] = -3.4e38f; bk[mt][r] = 0; }

    #pragma unroll
    for (int kt = 0; kt < 8; ++kt) {       // 16-code groups within wave's 128
        float iv = c2L[kh * 128 + kt * 16 + col];
        floatx4 aH[2], aM[2], aL[2];
        #pragma unroll
        for (int mt = 0; mt < 2; ++mt) {
            aH[mt][0] = iv; aH[mt][1] = iv; aH[mt][2] = iv; aH[mt][3] = iv;
            aM[mt][0] = 0.0f; aM[mt][1] = 0.0f; aM[mt][2] = 0.0f; aM[mt][3] = 0.0f;
            aL[mt][0] = 0.0f; aL[mt][1] = 0.0f; aL[mt][2] = 0.0f; aL[mt][3] = 0.0f;
        }
        // batch all 8 B-loads of this kt (load ILP), then 6 independent chains
        union V { uint4 u; short8 s; } BX[4], BY[4];
        #pragma unroll
        for (int ds = 0; ds < 4; ++ds) {
            int fi = (ds * 16 + kh * 8 + kt) * 64 + lane;
            BX[ds].u = bh4[fi];
            BY[ds].u = bl4[fi];
        }
        #pragma unroll
        for (int ds = 0; ds < 4; ++ds) {
            #pragma unroll
            for (int mt = 0; mt < 2; ++mt) {
                aH[mt] = __builtin_amdgcn_mfma_f32_16x16x32_bf16(Ah[mt][ds], BX[ds].s, aH[mt], 0, 0, 0);
                aM[mt] = __builtin_amdgcn_mfma_f32_16x16x32_bf16(Ah[mt][ds], BY[ds].s, aM[mt], 0, 0, 0);
                aL[mt] = __builtin_amdgcn_mfma_f32_16x16x32_bf16(Al[mt][ds], BX[ds].s, aL[mt], 0, 0, 0);
            }
        }
        // fold group into per-lane top-2
        int kc = kh * 128 + kt * 16 + col;
        #pragma unroll
        for (int mt = 0; mt < 2; ++mt)
            #pragma unroll
            for (int r = 0; r < 4; ++r) {
                float s = (aH[mt][r] + aM[mt][r]) + aL[mt][r];
                if (s > best[mt][r]) { second[mt][r] = best[mt][r]; best[mt][r] = s; bk[mt][r] = kc; }
                else if (s > second[mt][r]) second[mt][r] = s;
            }
    }

    // --- merge top-2 across the 16 cols (within wave) ---
    #pragma unroll
    for (int off = 1; off < 16; off <<= 1) {
        #pragma unroll
        for (int mt = 0; mt < 2; ++mt)
            #pragma unroll
            for (int r = 0; r < 4; ++r) {
                float ob = __shfl_xor(best[mt][r], off);
                float os = __shfl_xor(second[mt][r], off);
                int ok = __shfl_xor(bk[mt][r], off);
                float nb = fmaxf(best[mt][r], ob);
                float ns = fmaxf(fminf(best[mt][r], ob), fmaxf(second[mt][r], os));
                bk[mt][r] = (ob > best[mt][r]) ? ok : bk[mt][r];
                best[mt][r] = nb; second[mt][r] = ns;
            }
    }

    if (col == 0) {
        #pragma unroll
        for (int mt = 0; mt < 2; ++mt)
            #pragma unroll
            for (int r = 0; r < 4; ++r) {
                int nl = mh * 32 + mt * 16 + quad * 4 + r;
                mgB[kh][nl] = best[mt][r];
                mgS[kh][nl] = second[mt][r];
                mgK[kh][nl] = bk[mt][r];
            }
    }
    __syncthreads();

    // --- cross-half merge + idx/flag (one thread per n) ---
    if (t < MT) {
        float B1 = mgB[0][t], S = mgS[0][t];
        int KB = mgK[0][t];
        {
            float ob = mgB[1][t], os = mgS[1][t];
            int ok = mgK[1][t];
            float nb = fmaxf(B1, ob);
            float ns = fmaxf(fminf(B1, ob), fmaxf(S, os));
            KB = (ob > B1) ? ok : KB;
            B1 = nb; S = ns;
        }
        int n = n0 + t;
        bool fl = (B1 - S) < TAU;
        if (fl) {
            int slot = atomicAdd((int*)ws + WS_FLAGCNT, 1);
            if (slot < FLAG_CAP) ((int*)ws)[WS_LIST + slot] = n;
            else fl = false;
        }
        if (!fl) { out[OUT_IDX + n] = (float)KB; bkA[t] = KB; }
        else bkA[t] = -1;
    }
    __syncthreads();

    // --- epilogue: q write (coalesced over n) + loss partial ---
    const int nl = t & 63, dp = t >> 6;
    const int bkn = bkA[nl];
    float lsum = 0.0f;
    if (bkn >= 0) {
        const float4* __restrict__ cb4 = reinterpret_cast<const float4*>(cb);
        float* __restrict__ op = out + OUT_Q + (size_t)b * CHW + hw0 + nl;
        #pragma unroll
        for (int u = 0; u < 8; ++u) {
            float4 q4 = cb4[bkn * 32 + dp * 8 + u];
            int d = dp * 32 + u * 4;
            #pragma unroll
            for (int cc = 0; cc < 4; ++cc) {
                float zv = zs[(d + cc) * ZST + nl];
                float q = ((const float*)&q4)[cc];
                op[(size_t)(d + cc) * HW] = zv + (q - zv);   // straight-through rounding
                float tdf = zv - q;
                lsum = fmaf(tdf, tdf, lsum);
            }
        }
    }
    #pragma unroll
    for (int off = 32; off >= 1; off >>= 1) lsum += __shfl_down(lsum, off);
    if ((t & 63) == 0) lsw[w] = lsum;
    __syncthreads();
    if (t == 0) atomicAdd(ws + WS_LOSS, (lsw[0] + lsw[1]) + (lsw[2] + lsw[3]));
}

// ---------------------------------------------------------------------------
// Kernel 3: exact fallback for flagged n's. Dot unrolled x4 (float4 cb loads,
// 4 independent f64 accumulators).
// ---------------------------------------------------------------------------
__global__ void k_fallback(const float* __restrict__ z, const float* __restrict__ cb,
                           float* __restrict__ ws, float* __restrict__ out) {
    #pragma clang fp contract(off)
    const int tid = threadIdx.x;
    __shared__ float zsF[D];
    __shared__ float z2s;
    __shared__ float dvals[K];
    __shared__ int kidx[K];

    int cnt = ((const int*)ws)[WS_FLAGCNT];
    if (cnt > FLAG_CAP) cnt = FLAG_CAP;

    for (int li = blockIdx.x; li < cnt; li += gridDim.x) {
        const int n = ((const int*)ws)[WS_LIST + li];
        const int b = n >> 10;
        const int hw = n & 1023;

        if (tid < D) zsF[tid] = z[(size_t)b * CHW + (size_t)tid * HW + hw];
        __syncthreads();

        if (tid == 0) {
            float r[8];
            #pragma unroll
            for (int j = 0; j < 8; ++j) r[j] = zsF[j] * zsF[j];
            for (int i = 8; i < D; i += 8) {
                #pragma unroll
                for (int j = 0; j < 8; ++j) r[j] = r[j] + zsF[i + j] * zsF[i + j];
            }
            z2s = ((r[0] + r[1]) + (r[2] + r[3])) + ((r[4] + r[5]) + (r[6] + r[7]));
        }
        __syncthreads();

        {
            const float4* __restrict__ row4 =
                reinterpret_cast<const float4*>(cb + (size_t)tid * D);
            double a0 = 0.0, a1 = 0.0, a2 = 0.0, a3 = 0.0;
            #pragma unroll 4
            for (int d4 = 0; d4 < 32; ++d4) {
                float4 cv = row4[d4];
                const float* zz = &zsF[d4 * 4];
                a0 += (double)zz[0] * (double)cv.x;
                a1 += (double)zz[1] * (double)cv.y;
                a2 += (double)zz[2] * (double)cv.z;
                a3 += (double)zz[3] * (double)cv.w;
            }
            float zc = (float)((a0 + a1) + (a2 + a3));
            float dq = (z2s - 2.0f * zc) + ws[WS_C2 + tid];
            dvals[tid] = dq;
            kidx[tid] = tid;
        }
        __syncthreads();

        for (int s = K / 2; s > 0; s >>= 1) {
            if (tid < s) {
                float ov = dvals[tid + s]; int ok = kidx[tid + s];
                float mv = dvals[tid];     int mk2 = kidx[tid];
                if (ov < mv || (ov == mv && ok < mk2)) { dvals[tid] = ov; kidx[tid] = ok; }
            }
            __syncthreads();
        }
        const int bk = kidx[0];
        __syncthreads();

        float t2 = 0.0f;
        if (tid == 0) out[OUT_IDX + n] = (float)bk;
        if (tid < D) {
            float q = cb[(size_t)bk * D + tid];
            out[OUT_Q + (size_t)b * CHW + (size_t)tid * HW + hw] = zsF[tid] + (q - zsF[tid]);
            float t = zsF[tid] - q;
            t2 = t * t;
        }
        dvals[tid] = t2;
        __syncthreads();
        for (int s = K / 2; s > 0; s >>= 1) {
            if (tid < s) dvals[tid] += dvals[tid + s];
            __syncthreads();
        }
        if (tid == 0) atomicAdd(ws + WS_LOSS, dvals[0]);
        __syncthreads();
    }
}

// ---------------------------------------------------------------------------
// Kernel 4: EMA gather via direct LDS-atomic scatter (replaces sort+gather).
// 256 blocks x 1024: block = (pair p = blk>>2, d-quarter dh = blk&3).
// acc[K][32] fp32 in LDS; per round stage 128n x 32d (reg-buffered, next
// round's global load issued before the atomic phase), then each thread does
// 4 ds-atomic adds. Wave lanes span d -> 2-way banks (free); same-address
// contention impossible in-wave (lanes share n). dh==0 blocks also histogram
// counts. Partial-slot layout identical to before (finalize unchanged).
// ---------------------------------------------------------------------------
#define GN 2048
__global__ void __launch_bounds__(1024, 1)
k_gather(const float* __restrict__ z, const float* __restrict__ out,
         float* __restrict__ ws) {
    __shared__ float acc[K * 32];        // [k][d2], 32 KB
    __shared__ float zst[128 * 33];      // [nl][d2+pad], 16.5 KB
    __shared__ int ks[GN];               // 8 KB
    __shared__ int cntL[K];              // 1 KB

    const int t = threadIdx.x;
    const int p = blockIdx.x >> 2;       // pair 0..63
    const int dh = blockIdx.x & 3;       // d-quarter (32 d)

    #pragma unroll
    for (int i = 0; i < 8; ++i) acc[i * 1024 + t] = 0.0f;
    if (t < K) cntL[t] = 0;
    for (int j = t; j < GN; j += 1024)
        ks[j] = (int)out[OUT_IDX + (size_t)p * GN + j];
    __syncthreads();
    if (dh == 0) {
        for (int j = t; j < GN; j += 1024) atomicAdd(&cntL[ks[j]], 1);
    }

    const float4* __restrict__ z4 = reinterpret_cast<const float4*>(z);
    const int d2s = t >> 5;              // staging d index 0..31
    const int hl = t & 31;               // staging hw4 lane 0..31 (128 n)
    const int d2a = t & 31;              // atomic d index
    const int ng = t >> 5;               // atomic n-group 0..31

    float4 v = z4[(size_t)(2 * p) * (CHW / 4)
                  + (size_t)(dh * 32 + d2s) * (HW / 4) + hl];
    #pragma unroll 1
    for (int r = 0; r < 16; ++r) {       // 16 rounds x 128 n
        #pragma unroll
        for (int c = 0; c < 4; ++c)
            zst[(hl * 4 + c) * 33 + d2s] = ((const float*)&v)[c];
        __syncthreads();
        if (r < 15) {
            int n0r = (r + 1) * 128;
            int bb = n0r >> 10, hwb = n0r & 1023;
            v = z4[(size_t)(2 * p + bb) * (CHW / 4)
                   + (size_t)(dh * 32 + d2s) * (HW / 4) + (hwb >> 2) + hl];
        }
        #pragma unroll
        for (int i = 0; i < 4; ++i) {
            int nl = ng * 4 + i;
            int k = ks[r * 128 + nl];
            atomicAdd(&acc[k * 32 + d2a], zst[nl * 33 + d2a]);
        }
        __syncthreads();
    }

    // write out this block's quarter of the partial slot
    float* __restrict__ pout = ws + WS_PART + (size_t)p * PSTRIDE;
    #pragma unroll
    for (int it = 0; it < 8; ++it) {
        int idx = it * 1024 + t;
        int k = idx >> 5, d2 = idx & 31;
        pout[(size_t)k * D + dh * 32 + d2] = acc[idx];
    }
    if (dh == 0 && t < K) pout[K * D + t] = (float)cntL[t];
}

// ---------------------------------------------------------------------------
// Kernel 5: finalize (encsum/encbatch reduce + EMA outputs + losses).
// 128 blocks x 256; normc recomputed redundantly per block.
// ---------------------------------------------------------------------------
__global__ void k_finalize(const float* __restrict__ ema_count,
                           const float* __restrict__ ema_weight,
                           const float* __restrict__ ws, float* __restrict__ out) {
    #pragma clang fp contract(off)
    const int tid = threadIdx.x;
    const int blk = blockIdx.x;
    __shared__ float red[K];
    __shared__ float normc[K];

    const float DEC = 0.99f;
    const float OMD = (float)(1.0 - 0.99);

    float es = 0.0f;
    {
        const float* __restrict__ ps = ws + WS_PART + K * D + tid;
        #pragma unroll 8
        for (int g = 0; g < PBLK; ++g) es += ps[(size_t)g * PSTRIDE];
    }
    float nc = DEC * ema_count[tid] + OMD * es;
    red[tid] = nc;
    __syncthreads();
    for (int s = K / 2; s > 0; s >>= 1) {
        if (tid < s) red[tid] += red[tid + s];
        __syncthreads();
    }
    const float nt = red[0];
    normc[tid] = (nc + 1e-5f) / (nt + 0.00256f) * nt;
    __syncthreads();

    if (blk == 0) {
        out[OUT_NEWCNT + tid] = nc;
        if (tid == 0) {
            float m = ws[WS_LOSS] / 16777216.0f;
            out[OUT_CBLOSS] = m;
            out[OUT_COMMIT] = 0.25f * m;
        }
    }

    const int i = blk * 256 + tid;
    float eb = 0.0f;
    {
        const float* __restrict__ pb = ws + WS_PART + i;
        #pragma unroll 8
        for (int g = 0; g < PBLK; ++g) eb += pb[(size_t)g * PSTRIDE];
    }
    const int k = i >> 7;
    float nw = DEC * ema_weight[i] + OMD * eb;
    out[OUT_NEWW + i] = nw;
    out[OUT_NEWCB + i] = nw / normc[k];
}

// ---------------------------------------------------------------------------
extern "C" void kernel_launch(void* const* d_in, const int* in_sizes, int n_in,
                              void* d_out, int out_size, void* d_ws, size_t ws_size,
                              hipStream_t stream) {
    const float* z = (const float*)d_in[0];
    const float* cb = (const float*)d_in[1];
    const float* ema_count = (const float*)d_in[2];
    const float* ema_weight = (const float*)d_in[3];
    float* out = (float*)d_out;
    float* ws = (float*)d_ws;

    k_prep<<<17, 256, 0, stream>>>(cb, ws);
    k_main<<<N_TOT / MT, 256, 0, stream>>>(z, cb, ws, out);
    k_fallback<<<4096, 256, 0, stream>>>(z, cb, ws, out);
    k_gather<<<256, 1024, 0, stream>>>(z, out, ws);
    k_finalize<<<128, 256, 0, stream>>>(ema_count, ema_weight, ws, out);
}

// Round 8
// 236.690 us; speedup vs baseline: 1.2607x; 1.2607x over previous
//
#include <hip/hip_runtime.h>

// Problem constants
#define K 256
#define D 128
#define HW 1024          // H*W
#define CHW 131072       // D*HW (per-batch stride of z)
#define N_TOT 131072     // B*H*W
#define NELEM 16777216   // N_TOT * D

// Workspace layout (float/dword indices)
#define WS_C2 0
#define WS_ENCSUM 256
#define WS_ENCB 512
#define WS_LOSS 33280
#define WS_FLAGCNT 33281
#define WS_LIST 33282
#define FLAG_CAP 16384
#define WS_PART 49666            // 64 partial copies of (K*D + K)
#define PBLK 64
#define PSTRIDE 33024            // K*D + K
#define WS_CBT (WS_PART + PBLK * PSTRIDE)   // dead after k_main; ord overlay
#define WS_CBH 2195972           // bf16-hi swizzled B frags, 16384 dwords (16B aligned)
#define WS_CBL 2212356           // bf16-lo swizzled B frags, 16384 dwords
// total ws: 2228740*4 B = 8.91 MB
// After k_fallback completes, CBT/CBH/CBL and LIST are dead; k_sort/k_gather
// overlay: ord ushort[64][2048] at WS_CBT (spans into CBH/CBL); packed
// (startk<<16|cnt) at WS_LIST.

// Output layout (float indices, outputs concatenated in return order)
#define OUT_Q 0
#define OUT_IDX 16777216
#define OUT_COMMIT 16908288
#define OUT_CBLOSS 16908289
#define OUT_NEWCB 16908290
#define OUT_NEWCNT 16941058
#define OUT_NEWW 16941314

// Near-tie threshold. GEMM-score worst-case error vs exact is ~2-3e-6
// (hi/lo bf16 split; fp32 accum); 5e-5 keeps ~20x margin.
#define TAU 5e-5f
#define MT 64            // n-tile per block in k_main
#define ZST 68           // zs row stride (64 + 4 pad)

typedef __attribute__((ext_vector_type(8))) short short8;
typedef __attribute__((ext_vector_type(4))) float floatx4;

// Split x into truncated-bf16 hi and bf16 lo (hi exact-subtracted remainder).
__device__ __forceinline__ void cvt_split(const float* xv, short8* hi, short8* lo) {
    union U { uint32_t u[4]; short8 s; } H, L;
    #pragma unroll
    for (int p = 0; p < 4; ++p) {
        uint32_t u0 = __float_as_uint(xv[2 * p]);
        uint32_t u1 = __float_as_uint(xv[2 * p + 1]);
        H.u[p] = (u0 >> 16) | (u1 & 0xFFFF0000u);
        float h0 = __uint_as_float(u0 & 0xFFFF0000u);
        float h1 = __uint_as_float(u1 & 0xFFFF0000u);
        float l0 = xv[2 * p] - h0;
        float l1 = xv[2 * p + 1] - h1;
        L.u[p] = (__float_as_uint(l0) >> 16) | (__float_as_uint(l1) & 0xFFFF0000u);
    }
    *hi = H.s; *lo = L.s;
}

// ---------------------------------------------------------------------------
// Kernel 1: blk==0: c2 (numpy pairwise-8) + zero loss/flag. blk 1..16: bf16
// hi/lo split of cb into MFMA-B fragment order.
// ---------------------------------------------------------------------------
__global__ void k_prep(const float* __restrict__ cb, float* __restrict__ ws) {
    #pragma clang fp contract(off)
    const int blk = blockIdx.x, t = threadIdx.x;
    if (blk == 0) {
        int k = t;
        if (k == 0) { ws[WS_LOSS] = 0.0f; ((int*)ws)[WS_FLAGCNT] = 0; }
        const float* row = cb + (size_t)k * D;
        float r[8];
        #pragma unroll
        for (int j = 0; j < 8; ++j) r[j] = row[j] * row[j];
        for (int i = 8; i < D; i += 8) {
            #pragma unroll
            for (int j = 0; j < 8; ++j) r[j] = r[j] + row[i + j] * row[i + j];
        }
        ws[WS_C2 + k] = ((r[0] + r[1]) + (r[2] + r[3])) + ((r[4] + r[5]) + (r[6] + r[7]));
    } else {
        int e = (blk - 1) * 4 + (t >> 6);   // frag id 0..63
        int lane = t & 63;
        int ds = e >> 4, ktg = e & 15;
        int code = ktg * 16 + (lane & 15);
        int d0 = ds * 32 + (lane >> 4) * 8;
        float xv[8];
        #pragma unroll
        for (int j = 0; j < 8; ++j) xv[j] = cb[(size_t)code * D + d0 + j];
        short8 h, l;
        cvt_split(xv, &h, &l);
        union V { short8 s; uint4 u; } Hv, Lv;
        Hv.s = h; Lv.s = l;
        uint32_t* wsu = (uint32_t*)ws;
        reinterpret_cast<uint4*>(wsu + WS_CBH)[e * 64 + lane] = Hv.u;
        reinterpret_cast<uint4*>(wsu + WS_CBL)[e * 64 + lane] = Lv.u;
    }
}

// ---------------------------------------------------------------------------
// Kernel 2: MFMA GEMM-argmax, FULL K-SPLIT with register A. Wave w scores
// codes [64w,64w+64) for ALL 4 m-tiles (A-frags for 4 m-tiles in registers,
// ~128 VGPR — unlike failed R3 which put A in LDS + re-read z globally).
// Per kt: 8 B-loads feed 48 MFMAs (6 MFMA/load, 2x the R5 ratio); per-wave
// B traffic 32 KB (was 64). Per-code score order identical to R5
// (iv -> hh -> hl -> lh, single chain) => bit-identical scores.
// 4-way cross-wave merge in LDS. (256,2): ~230 VGPR, 2 blocks/CU.
// ---------------------------------------------------------------------------
__global__ void __launch_bounds__(256, 2)
k_main(const float* __restrict__ z, const float* __restrict__ cb,
       float* __restrict__ ws, float* __restrict__ out) {
    __shared__ float zs[D * ZST];      // zs[d][n], 34.8 KB
    __shared__ float c2L[K];           // -0.5*c2
    __shared__ float mgB[4][MT];
    __shared__ float mgS[4][MT];
    __shared__ int   mgK[4][MT];
    __shared__ int bkA[MT];
    __shared__ float lsw[4];

    const int t = threadIdx.x;
    const int blk = blockIdx.x;
    const int n0 = blk * MT;
    const int b = n0 >> 10;
    const int hw0 = n0 & 1023;

    // c2 -> LDS (pre-barrier): -0.5f*x is exact scaling.
    c2L[t] = -0.5f * ws[WS_C2 + t];

    // --- stage z tile: zs[d][n] via float4 over hw ---
    {
        const float4* __restrict__ z4 = reinterpret_cast<const float4*>(z);
        const size_t zbase4 = (size_t)b * (CHW / 4) + (hw0 >> 2);
        #pragma unroll
        for (int i = 0; i < 8; ++i) {
            int f = i * 256 + t;
            int dd = f >> 4, n4 = f & 15;
            float4 v = z4[zbase4 + (size_t)dd * (HW / 4) + n4];
            *reinterpret_cast<float4*>(&zs[dd * ZST + 4 * n4]) = v;
        }
    }
    __syncthreads();

    const int lane = t & 63, w = t >> 6;
    const int col = lane & 15, quad = lane >> 4;

    // --- A fragments: 4 m-tiles x 4 dsteps, hi+lo (32 short8 = 128 VGPR) ---
    short8 Ah[4][4], Al[4][4];
    {
        const int rbase = quad * 8 * ZST + col;
        #pragma unroll
        for (int mt = 0; mt < 4; ++mt)
            #pragma unroll
            for (int ds = 0; ds < 4; ++ds) {
                float xv[8];
                #pragma unroll
                for (int j = 0; j < 8; ++j)
                    xv[j] = zs[rbase + (ds * 32 + j) * ZST + mt * 16];
                cvt_split(xv, &Ah[mt][ds], &Al[mt][ds]);
            }
    }

    const uint32_t* wsu = (const uint32_t*)ws;
    const uint4* __restrict__ bh4 = reinterpret_cast<const uint4*>(wsu + WS_CBH);
    const uint4* __restrict__ bl4 = reinterpret_cast<const uint4*>(wsu + WS_CBL);

    float best[4][4], second[4][4];
    int bk[4][4];
    #pragma unroll
    for (int mt = 0; mt < 4; ++mt)
        #pragma unroll
        for (int r = 0; r < 4; ++r) { best[mt][r] = -3.4e38f; second[mt][r] = -3.4e38f; bk[mt][r] = 0; }

    #pragma unroll
    for (int kt = 0; kt < 4; ++kt) {       // 16-code groups within wave's 64
        float iv = c2L[w * 64 + kt * 16 + col];
        floatx4 acc[4];
        #pragma unroll
        for (int mt = 0; mt < 4; ++mt) {
            acc[mt][0] = iv; acc[mt][1] = iv; acc[mt][2] = iv; acc[mt][3] = iv;
        }
        // batch all 8 B-loads of this kt, then 48 MFMAs (4 m chains)
        union V { uint4 u; short8 s; } BX[4], BY[4];
        #pragma unroll
        for (int ds = 0; ds < 4; ++ds) {
            int fi = (ds * 16 + w * 4 + kt) * 64 + lane;
            BX[ds].u = bh4[fi];
            BY[ds].u = bl4[fi];
        }
        #pragma unroll
        for (int ds = 0; ds < 4; ++ds) {
            #pragma unroll
            for (int mt = 0; mt < 4; ++mt) {
                acc[mt] = __builtin_amdgcn_mfma_f32_16x16x32_bf16(Ah[mt][ds], BX[ds].s, acc[mt], 0, 0, 0);
                acc[mt] = __builtin_amdgcn_mfma_f32_16x16x32_bf16(Ah[mt][ds], BY[ds].s, acc[mt], 0, 0, 0);
                acc[mt] = __builtin_amdgcn_mfma_f32_16x16x32_bf16(Al[mt][ds], BX[ds].s, acc[mt], 0, 0, 0);
            }
        }
        // fold group into per-lane top-2
        int kc = w * 64 + kt * 16 + col;
        #pragma unroll
        for (int mt = 0; mt < 4; ++mt)
            #pragma unroll
            for (int r = 0; r < 4; ++r) {
                float s = acc[mt][r];
                if (s > best[mt][r]) { second[mt][r] = best[mt][r]; best[mt][r] = s; bk[mt][r] = kc; }
                else if (s > second[mt][r]) second[mt][r] = s;
            }
    }

    // --- merge top-2 across the 16 cols (within wave) ---
    #pragma unroll
    for (int off = 1; off < 16; off <<= 1) {
        #pragma unroll
        for (int mt = 0; mt < 4; ++mt)
            #pragma unroll
            for (int r = 0; r < 4; ++r) {
                float ob = __shfl_xor(best[mt][r], off);
                float os = __shfl_xor(second[mt][r], off);
                int ok = __shfl_xor(bk[mt][r], off);
                float nb = fmaxf(best[mt][r], ob);
                float ns = fmaxf(fminf(best[mt][r], ob), fmaxf(second[mt][r], os));
                bk[mt][r] = (ob > best[mt][r]) ? ok : bk[mt][r];
                best[mt][r] = nb; second[mt][r] = ns;
            }
    }

    if (col == 0) {
        #pragma unroll
        for (int mt = 0; mt < 4; ++mt)
            #pragma unroll
            for (int r = 0; r < 4; ++r) {
                int nl = mt * 16 + quad * 4 + r;
                mgB[w][nl] = best[mt][r];
                mgS[w][nl] = second[mt][r];
                mgK[w][nl] = bk[mt][r];
            }
    }
    __syncthreads();

    // --- cross-wave merge (4-way, ascending w = ascending code range) ---
    if (t < MT) {
        float B1 = mgB[0][t], S = mgS[0][t];
        int KB = mgK[0][t];
        #pragma unroll
        for (int ww = 1; ww < 4; ++ww) {
            float ob = mgB[ww][t], os = mgS[ww][t];
            int ok = mgK[ww][t];
            float nb = fmaxf(B1, ob);
            float ns = fmaxf(fminf(B1, ob), fmaxf(S, os));
            KB = (ob > B1) ? ok : KB;
            B1 = nb; S = ns;
        }
        int n = n0 + t;
        bool fl = (B1 - S) < TAU;
        if (fl) {
            int slot = atomicAdd((int*)ws + WS_FLAGCNT, 1);
            if (slot < FLAG_CAP) ((int*)ws)[WS_LIST + slot] = n;
            else fl = false;
        }
        if (!fl) { out[OUT_IDX + n] = (float)KB; bkA[t] = KB; }
        else bkA[t] = -1;
    }
    __syncthreads();

    // --- epilogue: q write (coalesced over n) + loss partial ---
    const int nl = t & 63, dp = t >> 6;
    const int bkn = bkA[nl];
    float lsum = 0.0f;
    if (bkn >= 0) {
        const float4* __restrict__ cb4 = reinterpret_cast<const float4*>(cb);
        float* __restrict__ op = out + OUT_Q + (size_t)b * CHW + hw0 + nl;
        #pragma unroll
        for (int u = 0; u < 8; ++u) {
            float4 q4 = cb4[bkn * 32 + dp * 8 + u];
            int d = dp * 32 + u * 4;
            #pragma unroll
            for (int cc = 0; cc < 4; ++cc) {
                float zv = zs[(d + cc) * ZST + nl];
                float q = ((const float*)&q4)[cc];
                op[(size_t)(d + cc) * HW] = zv + (q - zv);   // straight-through rounding
                float tdf = zv - q;
                lsum = fmaf(tdf, tdf, lsum);
            }
        }
    }
    #pragma unroll
    for (int off = 32; off >= 1; off >>= 1) lsum += __shfl_down(lsum, off);
    if ((t & 63) == 0) lsw[w] = lsum;
    __syncthreads();
    if (t == 0) atomicAdd(ws + WS_LOSS, (lsw[0] + lsw[1]) + (lsw[2] + lsw[3]));
}

// ---------------------------------------------------------------------------
// Kernel 3: exact fallback for flagged n's. Dot unrolled x4 (float4 cb loads,
// 4 independent f64 accumulators).
// ---------------------------------------------------------------------------
__global__ void k_fallback(const float* __restrict__ z, const float* __restrict__ cb,
                           float* __restrict__ ws, float* __restrict__ out) {
    #pragma clang fp contract(off)
    const int tid = threadIdx.x;
    __shared__ float zsF[D];
    __shared__ float z2s;
    __shared__ float dvals[K];
    __shared__ int kidx[K];

    int cnt = ((const int*)ws)[WS_FLAGCNT];
    if (cnt > FLAG_CAP) cnt = FLAG_CAP;

    for (int li = blockIdx.x; li < cnt; li += gridDim.x) {
        const int n = ((const int*)ws)[WS_LIST + li];
        const int b = n >> 10;
        const int hw = n & 1023;

        if (tid < D) zsF[tid] = z[(size_t)b * CHW + (size_t)tid * HW + hw];
        __syncthreads();

        if (tid == 0) {
            float r[8];
            #pragma unroll
            for (int j = 0; j < 8; ++j) r[j] = zsF[j] * zsF[j];
            for (int i = 8; i < D; i += 8) {
                #pragma unroll
                for (int j = 0; j < 8; ++j) r[j] = r[j] + zsF[i + j] * zsF[i + j];
            }
            z2s = ((r[0] + r[1]) + (r[2] + r[3])) + ((r[4] + r[5]) + (r[6] + r[7]));
        }
        __syncthreads();

        {
            const float4* __restrict__ row4 =
                reinterpret_cast<const float4*>(cb + (size_t)tid * D);
            double a0 = 0.0, a1 = 0.0, a2 = 0.0, a3 = 0.0;
            #pragma unroll 4
            for (int d4 = 0; d4 < 32; ++d4) {
                float4 cv = row4[d4];
                const float* zz = &zsF[d4 * 4];
                a0 += (double)zz[0] * (double)cv.x;
                a1 += (double)zz[1] * (double)cv.y;
                a2 += (double)zz[2] * (double)cv.z;
                a3 += (double)zz[3] * (double)cv.w;
            }
            float zc = (float)((a0 + a1) + (a2 + a3));
            float dq = (z2s - 2.0f * zc) + ws[WS_C2 + tid];
            dvals[tid] = dq;
            kidx[tid] = tid;
        }
        __syncthreads();

        for (int s = K / 2; s > 0; s >>= 1) {
            if (tid < s) {
                float ov = dvals[tid + s]; int ok = kidx[tid + s];
                float mv = dvals[tid];     int mk2 = kidx[tid];
                if (ov < mv || (ov == mv && ok < mk2)) { dvals[tid] = ov; kidx[tid] = ok; }
            }
            __syncthreads();
        }
        const int bk = kidx[0];
        __syncthreads();

        float t2 = 0.0f;
        if (tid == 0) out[OUT_IDX + n] = (float)bk;
        if (tid < D) {
            float q = cb[(size_t)bk * D + tid];
            out[OUT_Q + (size_t)b * CHW + (size_t)tid * HW + hw] = zsF[tid] + (q - zsF[tid]);
            float t = zsF[tid] - q;
            t2 = t * t;
        }
        dvals[tid] = t2;
        __syncthreads();
        for (int s = K / 2; s > 0; s >>= 1) {
            if (tid < s) dvals[tid] += dvals[tid + s];
            __syncthreads();
        }
        if (tid == 0) atomicAdd(ws + WS_LOSS, dvals[0]);
        __syncthreads();
    }
}

// ---------------------------------------------------------------------------
// Kernel 4a: per-batch-pair counting sort, run ONCE per pair. 1024 threads.
// ---------------------------------------------------------------------------
#define GN 2048
__global__ void k_sort(const float* __restrict__ out, float* __restrict__ ws) {
    __shared__ int idxs[GN];
    __shared__ int cnt[K];
    __shared__ int incl[K];
    __shared__ int fill[K];

    const int t = threadIdx.x;       // 1024
    const int p = blockIdx.x;        // batch pair

    if (t < K) cnt[t] = 0;
    __syncthreads();
    for (int j = t; j < GN; j += 1024) {
        int k = (int)out[OUT_IDX + (size_t)p * GN + j];
        idxs[j] = k;
        atomicAdd(&cnt[k], 1);
    }
    __syncthreads();
    if (t < K) incl[t] = cnt[t];
    __syncthreads();
    for (int off = 1; off < K; off <<= 1) {
        int v = 0;
        if (t < K) { v = incl[t]; if (t >= off) v += incl[t - off]; }
        __syncthreads();
        if (t < K) incl[t] = v;
        __syncthreads();
    }
    if (t < K) {
        const int st = incl[t] - cnt[t];
        fill[t] = st;
        ((int*)ws)[WS_LIST + p * K + t] = (st << 16) | cnt[t];           // packed startk|cnt
        ws[WS_PART + (size_t)p * PSTRIDE + K * D + t] = (float)cnt[t];   // partial count row
    }
    __syncthreads();

    unsigned short* ord = (unsigned short*)(ws + WS_CBT);
    for (int j = t; j < GN; j += 1024) {
        int k = idxs[j];
        int pos = atomicAdd(&fill[k], 1);
        ord[p * GN + pos] = (unsigned short)j;
    }
}

// ---------------------------------------------------------------------------
// Kernel 4b: EMA gather (bucket walk — fastest measured variant).
// Block = (pair p = blk>>4, 8-d chunk c = blk&15).
// ---------------------------------------------------------------------------
#define GZST 2052        // 512 float4 + 4
__global__ void __launch_bounds__(1024, 4)
k_gather(const float* __restrict__ z, float* __restrict__ ws) {
    __shared__ float zsg[8 * GZST];       // 8-d chunk x 2048 n, 65.7 KB
    __shared__ unsigned short ords[GN];   // 4 KB
    __shared__ int skc[K];                // packed startk|cnt

    const int t = threadIdx.x;
    const int p = blockIdx.x >> 4;     // batch pair
    const int c = blockIdx.x & 15;     // d-chunk (8 d)

    const unsigned short* ord = (const unsigned short*)(ws + WS_CBT);
    for (int j = t; j < GN; j += 1024) ords[j] = ord[p * GN + j];
    if (t < K) skc[t] = ((const int*)ws)[WS_LIST + p * K + t];

    // stage zsg[d2][n] for d = c*8 + d2
    const float4* __restrict__ z4 = reinterpret_cast<const float4*>(z);
    for (int j = t; j < 8 * 512; j += 1024) {
        int d2 = j >> 9, n4 = j & 511;
        int bb = n4 >> 8, hw4 = n4 & 255;
        float4 v = z4[(size_t)(2 * p + bb) * (CHW / 4)
                      + (size_t)(c * 8 + d2) * (HW / 4) + hw4];
        *reinterpret_cast<float4*>(&zsg[d2 * GZST + 4 * n4]) = v;
    }
    __syncthreads();

    const int dl = t & 7;
    const int k0 = (t >> 3) * 2;       // 2 k's per thread
    float* __restrict__ pout = ws + WS_PART + (size_t)p * PSTRIDE;
    const float* __restrict__ zrow = zsg + dl * GZST;
    #pragma unroll
    for (int kk = 0; kk < 2; ++kk) {
        int k = k0 + kk;
        int sc = skc[k];
        int s = sc >> 16, e = s + (sc & 0xFFFF);
        float a = 0.0f;
        for (int q = s; q < e; ++q) a += zrow[ords[q]];
        pout[(size_t)k * D + c * 8 + dl] = a;
    }
}

// ---------------------------------------------------------------------------
// Kernel 5: finalize (encsum/encbatch reduce + EMA outputs + losses).
// 128 blocks x 256; normc recomputed redundantly per block.
// ---------------------------------------------------------------------------
__global__ void k_finalize(const float* __restrict__ ema_count,
                           const float* __restrict__ ema_weight,
                           const float* __restrict__ ws, float* __restrict__ out) {
    #pragma clang fp contract(off)
    const int tid = threadIdx.x;
    const int blk = blockIdx.x;
    __shared__ float red[K];
    __shared__ float normc[K];

    const float DEC = 0.99f;
    const float OMD = (float)(1.0 - 0.99);

    float es = 0.0f;
    {
        const float* __restrict__ ps = ws + WS_PART + K * D + tid;
        #pragma unroll 8
        for (int g = 0; g < PBLK; ++g) es += ps[(size_t)g * PSTRIDE];
    }
    float nc = DEC * ema_count[tid] + OMD * es;
    red[tid] = nc;
    __syncthreads();
    for (int s = K / 2; s > 0; s >>= 1) {
        if (tid < s) red[tid] += red[tid + s];
        __syncthreads();
    }
    const float nt = red[0];
    normc[tid] = (nc + 1e-5f) / (nt + 0.00256f) * nt;
    __syncthreads();

    if (blk == 0) {
        out[OUT_NEWCNT + tid] = nc;
        if (tid == 0) {
            float m = ws[WS_LOSS] / 16777216.0f;
            out[OUT_CBLOSS] = m;
            out[OUT_COMMIT] = 0.25f * m;
        }
    }

    const int i = blk * 256 + tid;
    float eb = 0.0f;
    {
        const float* __restrict__ pb = ws + WS_PART + i;
        #pragma unroll 8
        for (int g = 0; g < PBLK; ++g) eb += pb[(size_t)g * PSTRIDE];
    }
    const int k = i >> 7;
    float nw = DEC * ema_weight[i] + OMD * eb;
    out[OUT_NEWW + i] = nw;
    out[OUT_NEWCB + i] = nw / normc[k];
}

// ---------------------------------------------------------------------------
extern "C" void kernel_launch(void* const* d_in, const int* in_sizes, int n_in,
                              void* d_out, int out_size, void* d_ws, size_t ws_size,
                              hipStream_t stream) {
    const float* z = (const float*)d_in[0];
    const float* cb = (const float*)d_in[1];
    const float* ema_count = (const float*)d_in[2];
    const float* ema_weight = (const float*)d_in[3];
    float* out = (float*)d_out;
    float* ws = (float*)d_ws;

    k_prep<<<17, 256, 0, stream>>>(cb, ws);
    k_main<<<N_TOT / MT, 256, 0, stream>>>(z, cb, ws, out);
    k_fallback<<<4096, 256, 0, stream>>>(z, cb, ws, out);
    k_sort<<<64, 1024, 0, stream>>>(out, ws);
    k_gather<<<1024, 1024, 0, stream>>>(z, ws);
    k_finalize<<<128, 256, 0, stream>>>(ema_count, ema_weight, ws, out);
}

// Round 9
// 225.797 us; speedup vs baseline: 1.3215x; 1.0482x over previous
//
#include <hip/hip_runtime.h>

// Problem constants
#define K 256
#define D 128
#define HW 1024          // H*W
#define CHW 131072       // D*HW (per-batch stride of z)
#define N_TOT 131072     // B*H*W
#define NELEM 16777216   // N_TOT * D

// Workspace layout (float/dword indices)
#define WS_C2 0
#define WS_ENCSUM 256
#define WS_ENCB 512
#define WS_LOSS 33280
#define WS_FLAGCNT 33281
#define WS_LIST 33282
#define FLAG_CAP 16384
#define WS_PART 49666            // 64 partial copies of (K*D + K)
#define PBLK 64
#define PSTRIDE 33024            // K*D + K
#define WS_CBT (WS_PART + PBLK * PSTRIDE)   // dead after fallback; ord overlay
#define WS_CBH 2195972           // bf16-hi swizzled B frags, 16384 dwords (16B aligned)
#define WS_CBL 2212356           // bf16-lo swizzled B frags, 16384 dwords
// total ws: 2228740*4 B = 8.91 MB
// After k_fallback completes, CBT/CBH/CBL and LIST are dead; k_sort/k_gather
// overlay: ord ushort[64][2048] at WS_CBT (spans into CBH/CBL); packed
// (startk<<16|cnt) at WS_LIST.

// Output layout (float indices, outputs concatenated in return order)
#define OUT_Q 0
#define OUT_IDX 16777216
#define OUT_COMMIT 16908288
#define OUT_CBLOSS 16908289
#define OUT_NEWCB 16908290
#define OUT_NEWCNT 16941058
#define OUT_NEWW 16941314

// Near-tie threshold. GEMM-score worst-case error vs exact is ~2-3e-6
// (hi/lo bf16 split; fp32 accum); 5e-5 keeps ~20x margin.
#define TAU 5e-5f
#define MT 64            // n-tile per block in k_main
#define ZST 68           // zs row stride (64 + 4 pad)

typedef __attribute__((ext_vector_type(8))) short short8;
typedef __attribute__((ext_vector_type(4))) float floatx4;

// Split x into truncated-bf16 hi and bf16 lo (hi exact-subtracted remainder).
__device__ __forceinline__ void cvt_split(const float* xv, short8* hi, short8* lo) {
    union U { uint32_t u[4]; short8 s; } H, L;
    #pragma unroll
    for (int p = 0; p < 4; ++p) {
        uint32_t u0 = __float_as_uint(xv[2 * p]);
        uint32_t u1 = __float_as_uint(xv[2 * p + 1]);
        H.u[p] = (u0 >> 16) | (u1 & 0xFFFF0000u);
        float h0 = __uint_as_float(u0 & 0xFFFF0000u);
        float h1 = __uint_as_float(u1 & 0xFFFF0000u);
        float l0 = xv[2 * p] - h0;
        float l1 = xv[2 * p + 1] - h1;
        L.u[p] = (__float_as_uint(l0) >> 16) | (__float_as_uint(l1) & 0xFFFF0000u);
    }
    *hi = H.s; *lo = L.s;
}

// ---------------------------------------------------------------------------
// Kernel 1 (widened: 68 blocks x 64 threads — old 17x256 used 7% of the chip
// on the critical path). blk 0..3: c2 for codes blk*64+t (pairwise-8, bit-
// identical); blk 4..67: one bf16 hi/lo frag (e = blk-4) per block.
// ---------------------------------------------------------------------------
__global__ void k_prep(const float* __restrict__ cb, float* __restrict__ ws) {
    #pragma clang fp contract(off)
    const int blk = blockIdx.x, t = threadIdx.x;
    if (blk < 4) {
        int k = blk * 64 + t;
        if (k == 0) { ws[WS_LOSS] = 0.0f; ((int*)ws)[WS_FLAGCNT] = 0; }
        const float* row = cb + (size_t)k * D;
        float r[8];
        #pragma unroll
        for (int j = 0; j < 8; ++j) r[j] = row[j] * row[j];
        for (int i = 8; i < D; i += 8) {
            #pragma unroll
            for (int j = 0; j < 8; ++j) r[j] = r[j] + row[i + j] * row[i + j];
        }
        ws[WS_C2 + k] = ((r[0] + r[1]) + (r[2] + r[3])) + ((r[4] + r[5]) + (r[6] + r[7]));
    } else {
        int e = blk - 4;                    // frag id 0..63
        int lane = t;                       // 64 threads = 64 lanes
        int ds = e >> 4, ktg = e & 15;
        int code = ktg * 16 + (lane & 15);
        int d0 = ds * 32 + (lane >> 4) * 8;
        float xv[8];
        #pragma unroll
        for (int j = 0; j < 8; ++j) xv[j] = cb[(size_t)code * D + d0 + j];
        short8 h, l;
        cvt_split(xv, &h, &l);
        union V { short8 s; uint4 u; } Hv, Lv;
        Hv.s = h; Lv.s = l;
        uint32_t* wsu = (uint32_t*)ws;
        reinterpret_cast<uint4*>(wsu + WS_CBH)[e * 64 + lane] = Hv.u;
        reinterpret_cast<uint4*>(wsu + WS_CBL)[e * 64 + lane] = Lv.u;
    }
}

// ---------------------------------------------------------------------------
// Kernel 2: MFMA GEMM-argmax, 2x2 wave split (REVERTED to the proven R5/R6
// version — 74.5 µs). Wave w = (mh=w>>1, kh=w&1): 2 m-tiles x 128 codes.
// Per kt: 8 batched B-loads feed 24 MFMAs. A-frags in registers from the
// fp32 padded zs tile. Ledger: occupancy bump (R6) null, chain-split (R7)
// null, full K-split (R8) -10% — this structure is the local optimum.
// ---------------------------------------------------------------------------
__global__ void __launch_bounds__(256, 3)
k_main(const float* __restrict__ z, const float* __restrict__ cb,
       float* __restrict__ ws, float* __restrict__ out) {
    __shared__ float zs[D * ZST];      // zs[d][n], 34.8 KB
    __shared__ float c2L[K];           // -0.5*c2
    __shared__ float mgB[2][MT];
    __shared__ float mgS[2][MT];
    __shared__ int   mgK[2][MT];
    __shared__ int bkA[MT];
    __shared__ float lsw[4];

    const int t = threadIdx.x;
    const int blk = blockIdx.x;
    const int n0 = blk * MT;
    const int b = n0 >> 10;
    const int hw0 = n0 & 1023;

    // c2 -> LDS (pre-barrier): -0.5f*x is exact scaling, bit-identical iv.
    c2L[t] = -0.5f * ws[WS_C2 + t];

    // --- stage z tile: zs[d][n] via float4 over hw ---
    {
        const float4* __restrict__ z4 = reinterpret_cast<const float4*>(z);
        const size_t zbase4 = (size_t)b * (CHW / 4) + (hw0 >> 2);
        #pragma unroll
        for (int i = 0; i < 8; ++i) {
            int f = i * 256 + t;
            int dd = f >> 4, n4 = f & 15;
            float4 v = z4[zbase4 + (size_t)dd * (HW / 4) + n4];
            *reinterpret_cast<float4*>(&zs[dd * ZST + 4 * n4]) = v;
        }
    }
    __syncthreads();

    const int lane = t & 63, w = t >> 6;
    const int col = lane & 15, quad = lane >> 4;
    const int kh = w & 1;              // code half: codes kh*128..+128
    const int mh = w >> 1;             // m half: n = mh*32..+32 (2 m-tiles)

    // --- A fragments: convert once, hold in regs (2 mt x 4 dsteps, hi+lo) ---
    short8 Ah[2][4], Al[2][4];
    {
        const int rbase = quad * 8 * ZST + mh * 32 + col;
        #pragma unroll
        for (int mt = 0; mt < 2; ++mt)
            #pragma unroll
            for (int ds = 0; ds < 4; ++ds) {
                float xv[8];
                #pragma unroll
                for (int j = 0; j < 8; ++j)
                    xv[j] = zs[rbase + (ds * 32 + j) * ZST + mt * 16];
                cvt_split(xv, &Ah[mt][ds], &Al[mt][ds]);
            }
    }

    const uint32_t* wsu = (const uint32_t*)ws;
    const uint4* __restrict__ bh4 = reinterpret_cast<const uint4*>(wsu + WS_CBH);
    const uint4* __restrict__ bl4 = reinterpret_cast<const uint4*>(wsu + WS_CBL);

    float best[2][4], second[2][4];
    int bk[2][4];
    #pragma unroll
    for (int mt = 0; mt < 2; ++mt)
        #pragma unroll
        for (int r = 0; r < 4; ++r) { best[mt][r] = -3.4e38f; second[mt][r] = -3.4e38f; bk[mt][r] = 0; }

    #pragma unroll
    for (int kt = 0; kt < 8; ++kt) {       // 16-code groups within wave's 128
        float iv = c2L[kh * 128 + kt * 16 + col];
        floatx4 acc[2];
        #pragma unroll
        for (int mt = 0; mt < 2; ++mt) {
            acc[mt][0] = iv; acc[mt][1] = iv; acc[mt][2] = iv; acc[mt][3] = iv;
        }
        // batch all 8 B-loads of this kt (load ILP), then the MFMA chain
        union V { uint4 u; short8 s; } BX[4], BY[4];
        #pragma unroll
        for (int ds = 0; ds < 4; ++ds) {
            int fi = (ds * 16 + kh * 8 + kt) * 64 + lane;
            BX[ds].u = bh4[fi];
            BY[ds].u = bl4[fi];
        }
        #pragma unroll
        for (int ds = 0; ds < 4; ++ds) {
            #pragma unroll
            for (int mt = 0; mt < 2; ++mt) {
                acc[mt] = __builtin_amdgcn_mfma_f32_16x16x32_bf16(Ah[mt][ds], BX[ds].s, acc[mt], 0, 0, 0);
                acc[mt] = __builtin_amdgcn_mfma_f32_16x16x32_bf16(Ah[mt][ds], BY[ds].s, acc[mt], 0, 0, 0);
                acc[mt] = __builtin_amdgcn_mfma_f32_16x16x32_bf16(Al[mt][ds], BX[ds].s, acc[mt], 0, 0, 0);
            }
        }
        // fold group into per-lane top-2
        int kc = kh * 128 + kt * 16 + col;
        #pragma unroll
        for (int mt = 0; mt < 2; ++mt)
            #pragma unroll
            for (int r = 0; r < 4; ++r) {
                float s = acc[mt][r];
                if (s > best[mt][r]) { second[mt][r] = best[mt][r]; best[mt][r] = s; bk[mt][r] = kc; }
                else if (s > second[mt][r]) second[mt][r] = s;
            }
    }

    // --- merge top-2 across the 16 cols (within wave) ---
    #pragma unroll
    for (int off = 1; off < 16; off <<= 1) {
        #pragma unroll
        for (int mt = 0; mt < 2; ++mt)
            #pragma unroll
            for (int r = 0; r < 4; ++r) {
                float ob = __shfl_xor(best[mt][r], off);
                float os = __shfl_xor(second[mt][r], off);
                int ok = __shfl_xor(bk[mt][r], off);
                float nb = fmaxf(best[mt][r], ob);
                float ns = fmaxf(fminf(best[mt][r], ob), fmaxf(second[mt][r], os));
                bk[mt][r] = (ob > best[mt][r]) ? ok : bk[mt][r];
                best[mt][r] = nb; second[mt][r] = ns;
            }
    }

    if (col == 0) {
        #pragma unroll
        for (int mt = 0; mt < 2; ++mt)
            #pragma unroll
            for (int r = 0; r < 4; ++r) {
                int nl = mh * 32 + mt * 16 + quad * 4 + r;
                mgB[kh][nl] = best[mt][r];
                mgS[kh][nl] = second[mt][r];
                mgK[kh][nl] = bk[mt][r];
            }
    }
    __syncthreads();

    // --- cross-half merge + idx/flag (one thread per n) ---
    if (t < MT) {
        float B1 = mgB[0][t], S = mgS[0][t];
        int KB = mgK[0][t];
        {
            float ob = mgB[1][t], os = mgS[1][t];
            int ok = mgK[1][t];
            float nb = fmaxf(B1, ob);
            float ns = fmaxf(fminf(B1, ob), fmaxf(S, os));
            KB = (ob > B1) ? ok : KB;
            B1 = nb; S = ns;
        }
        int n = n0 + t;
        bool fl = (B1 - S) < TAU;
        if (fl) {
            int slot = atomicAdd((int*)ws + WS_FLAGCNT, 1);
            if (slot < FLAG_CAP) ((int*)ws)[WS_LIST + slot] = n;
            else fl = false;
        }
        if (!fl) { out[OUT_IDX + n] = (float)KB; bkA[t] = KB; }
        else bkA[t] = -1;
    }
    __syncthreads();

    // --- epilogue: q write (coalesced over n) + loss partial; zs is fp32
    // exact, cb read row-major (2 cachelines/thread). ---
    const int nl = t & 63, dp = t >> 6;
    const int bkn = bkA[nl];
    float lsum = 0.0f;
    if (bkn >= 0) {
        const float4* __restrict__ cb4 = reinterpret_cast<const float4*>(cb);
        float* __restrict__ op = out + OUT_Q + (size_t)b * CHW + hw0 + nl;
        #pragma unroll
        for (int u = 0; u < 8; ++u) {
            float4 q4 = cb4[bkn * 32 + dp * 8 + u];
            int d = dp * 32 + u * 4;
            #pragma unroll
            for (int cc = 0; cc < 4; ++cc) {
                float zv = zs[(d + cc) * ZST + nl];
                float q = ((const float*)&q4)[cc];
                op[(size_t)(d + cc) * HW] = zv + (q - zv);   // straight-through rounding
                float tdf = zv - q;
                lsum = fmaf(tdf, tdf, lsum);
            }
        }
    }
    #pragma unroll
    for (int off = 32; off >= 1; off >>= 1) lsum += __shfl_down(lsum, off);
    if ((t & 63) == 0) lsw[w] = lsum;
    __syncthreads();
    if (t == 0) atomicAdd(ws + WS_LOSS, (lsw[0] + lsw[1]) + (lsw[2] + lsw[3]));
}

// ---------------------------------------------------------------------------
// Kernel 3: exact fallback for flagged n's. Dot unrolled x4 (float4 cb loads,
// 4 independent f64 accumulators).
// ---------------------------------------------------------------------------
__global__ void k_fallback(const float* __restrict__ z, const float* __restrict__ cb,
                           float* __restrict__ ws, float* __restrict__ out) {
    #pragma clang fp contract(off)
    const int tid = threadIdx.x;
    __shared__ float zsF[D];
    __shared__ float z2s;
    __shared__ float dvals[K];
    __shared__ int kidx[K];

    int cnt = ((const int*)ws)[WS_FLAGCNT];
    if (cnt > FLAG_CAP) cnt = FLAG_CAP;

    for (int li = blockIdx.x; li < cnt; li += gridDim.x) {
        const int n = ((const int*)ws)[WS_LIST + li];
        const int b = n >> 10;
        const int hw = n & 1023;

        if (tid < D) zsF[tid] = z[(size_t)b * CHW + (size_t)tid * HW + hw];
        __syncthreads();

        if (tid == 0) {
            float r[8];
            #pragma unroll
            for (int j = 0; j < 8; ++j) r[j] = zsF[j] * zsF[j];
            for (int i = 8; i < D; i += 8) {
                #pragma unroll
                for (int j = 0; j < 8; ++j) r[j] = r[j] + zsF[i + j] * zsF[i + j];
            }
            z2s = ((r[0] + r[1]) + (r[2] + r[3])) + ((r[4] + r[5]) + (r[6] + r[7]));
        }
        __syncthreads();

        {
            const float4* __restrict__ row4 =
                reinterpret_cast<const float4*>(cb + (size_t)tid * D);
            double a0 = 0.0, a1 = 0.0, a2 = 0.0, a3 = 0.0;
            #pragma unroll 4
            for (int d4 = 0; d4 < 32; ++d4) {
                float4 cv = row4[d4];
                const float* zz = &zsF[d4 * 4];
                a0 += (double)zz[0] * (double)cv.x;
                a1 += (double)zz[1] * (double)cv.y;
                a2 += (double)zz[2] * (double)cv.z;
                a3 += (double)zz[3] * (double)cv.w;
            }
            float zc = (float)((a0 + a1) + (a2 + a3));
            float dq = (z2s - 2.0f * zc) + ws[WS_C2 + tid];
            dvals[tid] = dq;
            kidx[tid] = tid;
        }
        __syncthreads();

        for (int s = K / 2; s > 0; s >>= 1) {
            if (tid < s) {
                float ov = dvals[tid + s]; int ok = kidx[tid + s];
                float mv = dvals[tid];     int mk2 = kidx[tid];
                if (ov < mv || (ov == mv && ok < mk2)) { dvals[tid] = ov; kidx[tid] = ok; }
            }
            __syncthreads();
        }
        const int bk = kidx[0];
        __syncthreads();

        float t2 = 0.0f;
        if (tid == 0) out[OUT_IDX + n] = (float)bk;
        if (tid < D) {
            float q = cb[(size_t)bk * D + tid];
            out[OUT_Q + (size_t)b * CHW + (size_t)tid * HW + hw] = zsF[tid] + (q - zsF[tid]);
            float t = zsF[tid] - q;
            t2 = t * t;
        }
        dvals[tid] = t2;
        __syncthreads();
        for (int s = K / 2; s > 0; s >>= 1) {
            if (tid < s) dvals[tid] += dvals[tid + s];
            __syncthreads();
        }
        if (tid == 0) atomicAdd(ws + WS_LOSS, dvals[0]);
        __syncthreads();
    }
}

// ---------------------------------------------------------------------------
// Kernel 4a: per-batch-pair counting sort, run ONCE per pair. 1024 threads.
// ---------------------------------------------------------------------------
#define GN 2048
__global__ void k_sort(const float* __restrict__ out, float* __restrict__ ws) {
    __shared__ int idxs[GN];
    __shared__ int cnt[K];
    __shared__ int incl[K];
    __shared__ int fill[K];

    const int t = threadIdx.x;       // 1024
    const int p = blockIdx.x;        // batch pair

    if (t < K) cnt[t] = 0;
    __syncthreads();
    for (int j = t; j < GN; j += 1024) {
        int k = (int)out[OUT_IDX + (size_t)p * GN + j];
        idxs[j] = k;
        atomicAdd(&cnt[k], 1);
    }
    __syncthreads();
    if (t < K) incl[t] = cnt[t];
    __syncthreads();
    for (int off = 1; off < K; off <<= 1) {
        int v = 0;
        if (t < K) { v = incl[t]; if (t >= off) v += incl[t - off]; }
        __syncthreads();
        if (t < K) incl[t] = v;
        __syncthreads();
    }
    if (t < K) {
        const int st = incl[t] - cnt[t];
        fill[t] = st;
        ((int*)ws)[WS_LIST + p * K + t] = (st << 16) | cnt[t];           // packed startk|cnt
        ws[WS_PART + (size_t)p * PSTRIDE + K * D + t] = (float)cnt[t];   // partial count row
    }
    __syncthreads();

    unsigned short* ord = (unsigned short*)(ws + WS_CBT);
    for (int j = t; j < GN; j += 1024) {
        int k = idxs[j];
        int pos = atomicAdd(&fill[k], 1);
        ord[p * GN + pos] = (unsigned short)j;
    }
}

// ---------------------------------------------------------------------------
// Kernel 4b: EMA gather (bucket walk — fastest measured variant).
// Block = (pair p = blk>>4, 8-d chunk c = blk&15).
// ---------------------------------------------------------------------------
#define GZST 2052        // 512 float4 + 4
__global__ void __launch_bounds__(1024, 4)
k_gather(const float* __restrict__ z, float* __restrict__ ws) {
    __shared__ float zsg[8 * GZST];       // 8-d chunk x 2048 n, 65.7 KB
    __shared__ unsigned short ords[GN];   // 4 KB
    __shared__ int skc[K];                // packed startk|cnt

    const int t = threadIdx.x;
    const int p = blockIdx.x >> 4;     // batch pair
    const int c = blockIdx.x & 15;     // d-chunk (8 d)

    const unsigned short* ord = (const unsigned short*)(ws + WS_CBT);
    for (int j = t; j < GN; j += 1024) ords[j] = ord[p * GN + j];
    if (t < K) skc[t] = ((const int*)ws)[WS_LIST + p * K + t];

    // stage zsg[d2][n] for d = c*8 + d2
    const float4* __restrict__ z4 = reinterpret_cast<const float4*>(z);
    for (int j = t; j < 8 * 512; j += 1024) {
        int d2 = j >> 9, n4 = j & 511;
        int bb = n4 >> 8, hw4 = n4 & 255;
        float4 v = z4[(size_t)(2 * p + bb) * (CHW / 4)
                      + (size_t)(c * 8 + d2) * (HW / 4) + hw4];
        *reinterpret_cast<float4*>(&zsg[d2 * GZST + 4 * n4]) = v;
    }
    __syncthreads();

    const int dl = t & 7;
    const int k0 = (t >> 3) * 2;       // 2 k's per thread
    float* __restrict__ pout = ws + WS_PART + (size_t)p * PSTRIDE;
    const float* __restrict__ zrow = zsg + dl * GZST;
    #pragma unroll
    for (int kk = 0; kk < 2; ++kk) {
        int k = k0 + kk;
        int sc = skc[k];
        int s = sc >> 16, e = s + (sc & 0xFFFF);
        float a = 0.0f;
        for (int q = s; q < e; ++q) a += zrow[ords[q]];
        pout[(size_t)k * D + c * 8 + dl] = a;
    }
}

// ---------------------------------------------------------------------------
// Kernel 5: finalize (encsum/encbatch reduce + EMA outputs + losses).
// 128 blocks x 256; normc recomputed redundantly per block.
// ---------------------------------------------------------------------------
__global__ void k_finalize(const float* __restrict__ ema_count,
                           const float* __restrict__ ema_weight,
                           const float* __restrict__ ws, float* __restrict__ out) {
    #pragma clang fp contract(off)
    const int tid = threadIdx.x;
    const int blk = blockIdx.x;
    __shared__ float red[K];
    __shared__ float normc[K];

    const float DEC = 0.99f;
    const float OMD = (float)(1.0 - 0.99);

    float es = 0.0f;
    {
        const float* __restrict__ ps = ws + WS_PART + K * D + tid;
        #pragma unroll 8
        for (int g = 0; g < PBLK; ++g) es += ps[(size_t)g * PSTRIDE];
    }
    float nc = DEC * ema_count[tid] + OMD * es;
    red[tid] = nc;
    __syncthreads();
    for (int s = K / 2; s > 0; s >>= 1) {
        if (tid < s) red[tid] += red[tid + s];
        __syncthreads();
    }
    const float nt = red[0];
    normc[tid] = (nc + 1e-5f) / (nt + 0.00256f) * nt;
    __syncthreads();

    if (blk == 0) {
        out[OUT_NEWCNT + tid] = nc;
        if (tid == 0) {
            float m = ws[WS_LOSS] / 16777216.0f;
            out[OUT_CBLOSS] = m;
            out[OUT_COMMIT] = 0.25f * m;
        }
    }

    const int i = blk * 256 + tid;
    float eb = 0.0f;
    {
        const float* __restrict__ pb = ws + WS_PART + i;
        #pragma unroll 8
        for (int g = 0; g < PBLK; ++g) eb += pb[(size_t)g * PSTRIDE];
    }
    const int k = i >> 7;
    float nw = DEC * ema_weight[i] + OMD * eb;
    out[OUT_NEWW + i] = nw;
    out[OUT_NEWCB + i] = nw / normc[k];
}

// ---------------------------------------------------------------------------
extern "C" void kernel_launch(void* const* d_in, const int* in_sizes, int n_in,
                              void* d_out, int out_size, void* d_ws, size_t ws_size,
                              hipStream_t stream) {
    const float* z = (const float*)d_in[0];
    const float* cb = (const float*)d_in[1];
    const float* ema_count = (const float*)d_in[2];
    const float* ema_weight = (const float*)d_in[3];
    float* out = (float*)d_out;
    float* ws = (float*)d_ws;

    k_prep<<<68, 64, 0, stream>>>(cb, ws);
    k_main<<<N_TOT / MT, 256, 0, stream>>>(z, cb, ws, out);
    k_fallback<<<4096, 256, 0, stream>>>(z, cb, ws, out);
    k_sort<<<64, 1024, 0, stream>>>(out, ws);
    k_gather<<<1024, 1024, 0, stream>>>(z, ws);
    k_finalize<<<128, 256, 0, stream>>>(ema_count, ema_weight, ws, out);
}